// Round 1
// baseline (200.724 us; speedup 1.0000x reference)
//
#include <hip/hip_runtime.h>

// Problem constants (match reference setup_inputs)
#define TT 32
#define BB 16
#define VV 50000
#define LL 400
#define MAX_OOV 100
#define EV (VV + MAX_OOV)       // 50100
#define EV4 (EV / 4)            // 12525
#define V4 (VV / 4)             // 12500

// Kernel 1: out[t,b,v] = p_gen[t,b] * vocab[t,b,v] for v<V; 0 for V<=v<ev.
// Fully coalesced float4 loads/stores. blockIdx.y = t*B+b row.
__global__ __launch_bounds__(256) void fdl_gate_kernel(
    const float* __restrict__ vocab,
    const float* __restrict__ pgen,
    float* __restrict__ out)
{
    const int row = blockIdx.y;                                  // t*B + b
    const int i   = blockIdx.x * blockDim.x + threadIdx.x;       // float4 slot
    if (i >= EV4) return;

    const float p = pgen[row];
    float4* __restrict__ o4 = reinterpret_cast<float4*>(out + (size_t)row * EV);

    if (i < V4) {
        const float4* __restrict__ v4 =
            reinterpret_cast<const float4*>(vocab + (size_t)row * VV);
        float4 v = v4[i];
        v.x *= p; v.y *= p; v.z *= p; v.w *= p;
        o4[i] = v;
    } else {
        o4[i] = make_float4(0.f, 0.f, 0.f, 0.f);
    }
}

// Kernel 2: scatter-add copy distribution.
// out[t,b, ids[b,l]] += (1 - p_gen[t,b]) * attn[t,b,l]
__global__ __launch_bounds__(256) void fdl_scatter_kernel(
    const float* __restrict__ attn,
    const float* __restrict__ pgen,
    const int* __restrict__ ids,
    float* __restrict__ out)
{
    const int idx = blockIdx.x * blockDim.x + threadIdx.x;
    if (idx >= TT * BB * LL) return;

    const int l  = idx % LL;
    const int tb = idx / LL;          // t*B + b
    const int b  = tb % BB;

    const float p = pgen[tb];
    const float a = attn[idx];
    const int   id = ids[b * LL + l]; // in [0, EV)

    atomicAdd(out + (size_t)tb * EV + id, (1.0f - p) * a);
}

extern "C" void kernel_launch(void* const* d_in, const int* in_sizes, int n_in,
                              void* d_out, int out_size, void* d_ws, size_t ws_size,
                              hipStream_t stream) {
    const float* vocab = (const float*)d_in[0];   // [T,B,V]
    const float* attn  = (const float*)d_in[1];   // [T,B,L]
    const float* pgen  = (const float*)d_in[2];   // [T,B,1]
    const int*   ids   = (const int*)d_in[3];     // [B,L]
    float* out = (float*)d_out;                   // [T,B,EV]

    // Gate + zero-pad: full output coverage (harness poisons d_out with 0xAA).
    dim3 gateGrid((EV4 + 255) / 256, TT * BB);
    fdl_gate_kernel<<<gateGrid, 256, 0, stream>>>(vocab, pgen, out);

    // Scatter-add copy distribution (runs after gate on same stream).
    const int n_scatter = TT * BB * LL;           // 204800
    fdl_scatter_kernel<<<(n_scatter + 255) / 256, 256, 0, stream>>>(
        attn, pgen, ids, out);
}